// Round 6
// baseline (2852.759 us; speedup 1.0000x reference)
//
#include <hip/hip_runtime.h>
#include <math.h>
#include <stdint.h>

// ============================================================================
// TopDownNet via split-f16 MFMA, R10: 2-D wave split (4 nt-groups x 2 sg).
// R9 (2407 us): MfmaUtil 57%; LDS pipe now critical: 5.5e7 ds_read_b128
// (~1.08 ms/CU) + 2.65e8 conflict cycles (0.43 ms) > MFMA floor (1.30 ms
// demand at 4.85cyc). Cause: of-eighth split -> every activation read 8x.
// R10: wave wu owns 64 of (wn=wu&3 -> tiles 4wn..4wn+3) x 32 samples
// (sg=wu>>2 -> sample-frags 2sg,2sg+1):
//  - activation reads per wave halve (4 b128/chunk) -> LDS demand ~0.75 ms,
//    below MFMA floor; conflicts should halve proportionally.
//  - weight loads per wave double (8 uint4/chunk, ~55 GB L1/L2 total) --
//    VMEM overlaps MFMA, L2 has headroom.
//  - acc stays 64 regs -> 128/wave cap, 4 waves/SIMD (16/CU) retained.
// Split math (validated R5-R9, absmax 3.8e-6): x = xh + xl*2^-11, w likewise;
//   acc1 += xh*wh ; acc2 += xh*wl + xl*wh ; result = acc1 + acc2/2048.
// Fragment layouts (gfx950 16x16x32): A row=l&15 (of), k=(l>>4)*8+i;
//   B col=l&15 (sample), same k; D row=(l>>4)*4+r, col=l&15.
// ============================================================================

typedef _Float16 half8 __attribute__((ext_vector_type(8)));
typedef __fp16 fp16x2 __attribute__((ext_vector_type(2)));  // cvt_pkrtz native
typedef float f32x4 __attribute__((ext_vector_type(4)));

constexpr int KS = 10;
constexpr int RSTR = 584;  // f16/row: 288 hi + 288 lo + 8 pad
constexpr float SPLIT_S = 2048.f;
constexpr float SPLIT_INV = 1.f / 2048.f;

// W^T fragment streams (layout unchanged since R5; wave-decomposition-agnostic).
// Frag idx: O1 0-143, M1 144-287, O2 288-415, M2 416-543, M3 544-671.
__device__ __align__(16) _Float16 g_Wh[672 * 512];
__device__ __align__(16) _Float16 g_Wl[672 * 512];
// M1 park: 2048 blocks x 8 waves x 8 uint4 x 64 lanes (wave-private slots).
__device__ __align__(16) uint4 g_park[2048u * 8u * 8u * 64u];

__global__ void prep_w(const float* __restrict__ O1w, const float* __restrict__ M1w,
                       const float* __restrict__ O2w, const float* __restrict__ M2w,
                       const float* __restrict__ M3w) {
  const int bid = blockIdx.x, l = threadIdx.x;
  const float* W; int Ksrc, f;
  if (bid < 144)      { W = O1w; Ksrc = 270; f = bid; }
  else if (bid < 288) { W = M1w; Ksrc = 270; f = bid - 144; }
  else if (bid < 416) { W = O2w; Ksrc = 256; f = bid - 288; }
  else if (bid < 544) { W = M2w; Ksrc = 256; f = bid - 416; }
  else                { W = M3w; Ksrc = 256; f = bid - 544; }
  const int c = f >> 4, nt = f & 15, g = l >> 4, s = l & 15;
  const int of = nt * 16 + s;
  union { half8 h; uint4 u; } hv, lv;
#pragma unroll
  for (int i = 0; i < 8; ++i) {
    const int k = c * 32 + g * 8 + i;
    const float w = (k < Ksrc) ? W[k * 256 + of] : 0.f;  // zero-pad K 270..287
    const _Float16 h = (_Float16)w;
    hv.h[i] = h;
    lv.h[i] = (_Float16)((w - (float)h) * SPLIT_S);
  }
  ((uint4*)g_Wh)[bid * 64 + l] = hv.u;
  ((uint4*)g_Wl)[bid * 64 + l] = lv.u;
}

__device__ __forceinline__ half8 as_half8(uint4 u) {
  union { uint4 u4; half8 h; } c; c.u4 = u; return c.h;
}
__device__ __forceinline__ f32x4 mfma16(half8 a, half8 b, f32x4 c) {
  return __builtin_amdgcn_mfma_f32_16x16x32_f16(a, b, c, 0, 0, 0);
}
__device__ __forceinline__ uint32_t h2bits(fp16x2 h) {
  union { fp16x2 h2; uint32_t u; } c; c.h2 = h; return c.u;
}

struct PK { uint2 hi, lo; };
// RTZ split-pack of 4 f32 -> 4 f16-hi + 4 f16-lo (residual * 2048).
__device__ __forceinline__ PK split4(float v0, float v1, float v2, float v3) {
  fp16x2 h01 = __builtin_amdgcn_cvt_pkrtz(v0, v1);
  fp16x2 h23 = __builtin_amdgcn_cvt_pkrtz(v2, v3);
  fp16x2 l01 = __builtin_amdgcn_cvt_pkrtz((v0 - (float)h01[0]) * SPLIT_S,
                                          (v1 - (float)h01[1]) * SPLIT_S);
  fp16x2 l23 = __builtin_amdgcn_cvt_pkrtz((v2 - (float)h23[0]) * SPLIT_S,
                                          (v3 - (float)h23[1]) * SPLIT_S);
  PK r;
  r.hi = make_uint2(h2bits(h01), h2bits(h23));
  r.lo = make_uint2(h2bits(l01), h2bits(l23));
  return r;
}
__device__ __forceinline__ void split1(float v, _Float16& h, _Float16& l) {
  h = (_Float16)v;
  l = (_Float16)((v - (float)h) * SPLIT_S);
}

__device__ __forceinline__ void zero42(f32x4 a1[4][2], f32x4 a2[4][2]) {
#pragma unroll
  for (int n = 0; n < 4; ++n)
#pragma unroll
    for (int sf = 0; sf < 2; ++sf) {
      a1[n][sf] = (f32x4){0.f, 0.f, 0.f, 0.f};
      a2[n][sf] = (f32x4){0.f, 0.f, 0.f, 0.f};
    }
}

// GEMM over CHUNKS K-chunks of 32: wave computes of-tiles {4wn..4wn+3} for
// samples 32sg..32sg+31. Per c: 8 global dwordx4 (weights) + 4 ds_read_b128
// (B hi/lo for 2 sample-frags) + 24 MFMA.
template <int CHUNKS>
__device__ __forceinline__ void lgemm(f32x4 a1[4][2], f32x4 a2[4][2],
                                      const _Float16* __restrict__ Xs,
                                      const uint4* __restrict__ Wh,
                                      const uint4* __restrict__ Wl,
                                      int wn, int sg, int g, int s) {
#pragma unroll 1
  for (int c = 0; c < CHUNKS; ++c) {
    uint4 wh[4], wl[4];
#pragma unroll
    for (int n = 0; n < 4; ++n) {
      wh[n] = Wh[(c * 16 + 4 * wn + n) * 64];
      wl[n] = Wl[(c * 16 + 4 * wn + n) * 64];
    }
#pragma unroll
    for (int sf = 0; sf < 2; ++sf) {
      const _Float16* xp =
          Xs + (16 * (2 * sg + sf) + s) * RSTR + c * 32 + g * 8;
      half8 bh = *(const half8*)xp;          // hi plane (16B aligned)
      half8 bl = *(const half8*)(xp + 288);  // lo plane
#pragma unroll
      for (int n = 0; n < 4; ++n) {
        a1[n][sf] = mfma16(as_half8(wh[n]), bh, a1[n][sf]);
        a2[n][sf] = mfma16(as_half8(wh[n]), bl, a2[n][sf]);
        a2[n][sf] = mfma16(as_half8(wl[n]), bh, a2[n][sf]);
      }
    }
  }
}

// relu(acc1 + acc2/2048 + bias) split-packed into X planes.
__device__ __forceinline__ void epi_write(const f32x4 a1[4][2], const f32x4 a2[4][2],
                                          const float* __restrict__ bias,  // global
                                          _Float16* __restrict__ Xs,
                                          int wn, int sg, int g, int s) {
#pragma unroll
  for (int n = 0; n < 4; ++n) {
    const float4 bv = *(const float4*)(bias + (4 * wn + n) * 16 + 4 * g);
#pragma unroll
    for (int sf = 0; sf < 2; ++sf) {
      const float v0 = fmaxf(fmaf(a2[n][sf][0], SPLIT_INV, a1[n][sf][0]) + bv.x, 0.f);
      const float v1 = fmaxf(fmaf(a2[n][sf][1], SPLIT_INV, a1[n][sf][1]) + bv.y, 0.f);
      const float v2 = fmaxf(fmaf(a2[n][sf][2], SPLIT_INV, a1[n][sf][2]) + bv.z, 0.f);
      const float v3 = fmaxf(fmaf(a2[n][sf][3], SPLIT_INV, a1[n][sf][3]) + bv.w, 0.f);
      const PK p = split4(v0, v1, v2, v3);
      _Float16* yp =
          Xs + (16 * (2 * sg + sf) + s) * RSTR + (4 * wn + n) * 16 + 4 * g;
      *(uint2*)yp = p.hi;
      *(uint2*)(yp + 288) = p.lo;
    }
  }
}

// M1 epilogue -> coalesced park in global (wave-private slot, 8 uint4/lane).
// pk[n] = hi of nt n (sf0 in .xy, sf1 in .zw); pk[4+n] = lo likewise.
__device__ __forceinline__ void epi_park(const f32x4 a1[4][2], const f32x4 a2[4][2],
                                         const float* __restrict__ bias,
                                         uint4* __restrict__ slot,
                                         int wn, int g, int l) {
#pragma unroll
  for (int n = 0; n < 4; ++n) {
    const float4 bv = *(const float4*)(bias + (4 * wn + n) * 16 + 4 * g);
    PK q[2];
#pragma unroll
    for (int sf = 0; sf < 2; ++sf) {
      const float v0 = fmaxf(fmaf(a2[n][sf][0], SPLIT_INV, a1[n][sf][0]) + bv.x, 0.f);
      const float v1 = fmaxf(fmaf(a2[n][sf][1], SPLIT_INV, a1[n][sf][1]) + bv.y, 0.f);
      const float v2 = fmaxf(fmaf(a2[n][sf][2], SPLIT_INV, a1[n][sf][2]) + bv.z, 0.f);
      const float v3 = fmaxf(fmaf(a2[n][sf][3], SPLIT_INV, a1[n][sf][3]) + bv.w, 0.f);
      q[sf] = split4(v0, v1, v2, v3);
    }
    slot[n * 64 + l]       = make_uint4(q[0].hi.x, q[0].hi.y, q[1].hi.x, q[1].hi.y);
    slot[(4 + n) * 64 + l] = make_uint4(q[0].lo.x, q[0].lo.y, q[1].lo.x, q[1].lo.y);
  }
}

// unpark loaded uint4s -> X planes.
__device__ __forceinline__ void unpark_write(const uint4 pk[8],
                                             _Float16* __restrict__ Xs,
                                             int wn, int sg, int g, int s) {
#pragma unroll
  for (int n = 0; n < 4; ++n) {
    const uint4 hi = pk[n];
    const uint4 lo = pk[4 + n];
#pragma unroll
    for (int sf = 0; sf < 2; ++sf) {
      _Float16* yp =
          Xs + (16 * (2 * sg + sf) + s) * RSTR + (4 * wn + n) * 16 + 4 * g;
      *(uint2*)yp = sf ? make_uint2(hi.z, hi.w) : make_uint2(hi.x, hi.y);
      *(uint2*)(yp + 288) = sf ? make_uint2(lo.z, lo.w) : make_uint2(lo.x, lo.y);
    }
  }
}

__global__ __launch_bounds__(512, 4) void topdown_mfma(
    const float* __restrict__ towers, const float* __restrict__ aggregate,
    const float* __restrict__ O1b, const float* __restrict__ O2b,
    const float* __restrict__ O3w, const float* __restrict__ O3b,
    const float* __restrict__ M1b, const float* __restrict__ M2b,
    const float* __restrict__ M3b, float* __restrict__ out) {
  __shared__ __align__(16) _Float16 Xs[64 * RSTR];  // 74752 B
  __shared__ __align__(16) float scr[64][4];        // 1 KB cross-wave reduce
  const int t = threadIdx.x, l = t & 63;
  const int wu = __builtin_amdgcn_readfirstlane(t >> 6);  // wave id 0..7
  const int wn = wu & 3;   // of-group: tiles 4wn..4wn+3 (64 features)
  const int sg = wu >> 2;  // sample-group: samples 32sg..32sg+31
  const int g = l >> 4, s = l & 15;
  const int n0 = blockIdx.x * 64;
  uint4* park = g_park + ((size_t)blockIdx.x * 8 + (size_t)wu) * (8 * 64);

  // init X: logical features 0..255 = aggregate, 256..287 = 0 (both planes).
  for (int idx = t; idx < 64 * 288; idx += 512) {
    const int ss = idx / 288, f = idx - ss * 288;
    const float v = (f < 256) ? aggregate[f] : 0.f;
    _Float16 h, lo; split1(v, h, lo);
    Xs[ss * RSTR + f] = h;
    Xs[ss * RSTR + 288 + f] = lo;
  }

  float prod = 1.f;
  const float o3bias = O3b[0];
  f32x4 a1[4][2], a2[4][2];

  const uint4* WhL = (const uint4*)g_Wh + l;
  const uint4* WlL = (const uint4*)g_Wl + l;

  for (int kk = 0; kk < KS; ++kk) {
    const int tbase = (KS - 1 - kk) * 14;  // reference flips along K
    // tower slice -> logical features 256..269 (both planes)
    for (int idx = t; idx < 64 * 14; idx += 512) {
      const int ss = idx / 14, f = idx - ss * 14;
      const float v = towers[(size_t)(n0 + ss) * (KS * 14) + tbase + f];
      _Float16 h, lo; split1(v, h, lo);
      Xs[ss * RSTR + 256 + f] = h;
      Xs[ss * RSTR + 288 + 256 + f] = lo;
    }
    __syncthreads();  // (a) towers + previous A' visible

    // ---- M1 over X=[A,T]; result -> global park
    zero42(a1, a2);
    lgemm<9>(a1, a2, Xs, WhL + 144 * 64, WlL + 144 * 64, wn, sg, g, s);
    epi_park(a1, a2, M1b, park, wn, g, l);

    // ---- O1 over X
    zero42(a1, a2);
    lgemm<9>(a1, a2, Xs, WhL, WlL, wn, sg, g, s);
    __syncthreads();  // (b) all X reads done
    epi_write(a1, a2, O1b, Xs, wn, sg, g, s);  // X[0..255] <- h1
    __syncthreads();  // (c) h1 visible

    // ---- O2 over h1
    zero42(a1, a2);
    lgemm<8>(a1, a2, Xs, WhL + 288 * 64, WlL + 288 * 64, wn, sg, g, s);

    // unpark loads issued now (wave-private; latency hides under O3 tail)
    asm volatile("" ::: "memory");
    uint4 pk[8];
#pragma unroll
    for (int q = 0; q < 8; ++q) pk[q] = park[q * 64 + l];

    // O3 tail: relu(O2) dot O3w -> per-sample partials over this wave's 64 of
    float tp[2] = {0.f, 0.f};
#pragma unroll
    for (int n = 0; n < 4; ++n) {
      const int ob = (4 * wn + n) * 16 + 4 * g;
      const float4 bv = *(const float4*)(O2b + ob);
      const float4 ov = *(const float4*)(O3w + ob);
      const float bb[4] = {bv.x, bv.y, bv.z, bv.w};
      const float oo[4] = {ov.x, ov.y, ov.z, ov.w};
#pragma unroll
      for (int sf = 0; sf < 2; ++sf)
#pragma unroll
        for (int r = 0; r < 4; ++r)
          tp[sf] += fmaxf(fmaf(a2[n][sf][r], SPLIT_INV, a1[n][sf][r]) + bb[r], 0.f) * oo[r];
    }
#pragma unroll
    for (int sf = 0; sf < 2; ++sf) {  // sum over the 4 g-groups
      tp[sf] += __shfl_xor(tp[sf], 16);
      tp[sf] += __shfl_xor(tp[sf], 32);
    }
    if (g == 0) {  // 4 wn-writers per sample row
#pragma unroll
      for (int sf = 0; sf < 2; ++sf) scr[16 * (2 * sg + sf) + s][wn] = tp[sf];
    }
    __syncthreads();  // (d) scr ready; all h1 reads done

    unpark_write(pk, Xs, wn, sg, g, s);  // X <- A' (M1 result)
    if (t < 64) {
      const float4 sv = *(const float4*)(scr[t]);
      prod *= 1.f / (1.f + expf(-(sv.x + sv.y + sv.z + sv.w + o3bias)));
    }
    __syncthreads();  // (e) A' visible

    // ---- M2 (in place)
    zero42(a1, a2);
    lgemm<8>(a1, a2, Xs, WhL + 416 * 64, WlL + 416 * 64, wn, sg, g, s);
    __syncthreads();  // (f) reads done
    epi_write(a1, a2, M2b, Xs, wn, sg, g, s);
    __syncthreads();  // (g)

    // ---- M3 (in place); next-iter sync (a) covers the write->read edge
    zero42(a1, a2);
    lgemm<8>(a1, a2, Xs, WhL + 544 * 64, WlL + 544 * 64, wn, sg, g, s);
    __syncthreads();  // (h) reads done
    epi_write(a1, a2, M3b, Xs, wn, sg, g, s);
  }

  if (t < 64) out[n0 + t] = prod;
}

extern "C" void kernel_launch(void* const* d_in, const int* in_sizes, int n_in,
                              void* d_out, int out_size, void* d_ws, size_t ws_size,
                              hipStream_t stream) {
  const float* towers    = (const float*)d_in[0];
  const float* aggregate = (const float*)d_in[1];
  const float* M1w = (const float*)d_in[2];
  const float* M1b = (const float*)d_in[3];
  const float* M2w = (const float*)d_in[4];
  const float* M2b = (const float*)d_in[5];
  const float* M3w = (const float*)d_in[6];
  const float* M3b = (const float*)d_in[7];
  const float* O1w = (const float*)d_in[8];
  const float* O1b = (const float*)d_in[9];
  const float* O2w = (const float*)d_in[10];
  const float* O2b = (const float*)d_in[11];
  const float* O3w = (const float*)d_in[12];
  const float* O3b = (const float*)d_in[13];
  float* out = (float*)d_out;

  prep_w<<<672, 64, 0, stream>>>(O1w, M1w, O2w, M2w, M3w);

  const int nblocks = out_size / 64;  // 2048 blocks x 512 threads (8 waves)
  topdown_mfma<<<nblocks, 512, 0, stream>>>(towers, aggregate, O1b, O2b, O3w,
                                            O3b, M1b, M2b, M3b, out);
}